// Round 2
// baseline (267.795 us; speedup 1.0000x reference)
//
#include <hip/hip_runtime.h>

// Embed3D: out[n,l, c*40 + 2k + {0,1}] = {sin,cos}(x[n,l,1+c] * div_term[k])
// 524288 positions x 120 floats. One thread per (rem, position-set):
// rem = which of the 30 float4s per position; each thread handles PPT=16
// positions (stride 32), processed in 2 chunks of 8 to keep VGPR pressure
// (and 2-blocks/CU residency) identical to the PPT=8 version.
// Block (30,32) = 15 waves writes a fully contiguous 120-KB span.
// Stores are NON-TEMPORAL: output is write-once (251.7 MB ~= L3 size), so we
// bypass the L2/L3 allocate path that we believe throttled stores to ~2.5 TB/s.
// NOTE: __builtin_nontemporal_store needs a NATIVE vector type, not
// HIP_vector_type<float,4> -> use ext_vector_type(4) and cast the pointer.

typedef float nfloat4 __attribute__((ext_vector_type(4)));

constexpr float INV_2PI = 0.15915494309189535f;  // hw v_sin/v_cos take revolutions
constexpr int PPT   = 16;                        // positions per thread
constexpr int CHUNK = 8;                         // load/compute batch (VGPR control)

__global__ __launch_bounds__(960) void Embed3D_kernel(
    const float4* __restrict__ x4,       // (524288) float4: [.,p1,p2,p3]
    const float2* __restrict__ div2,     // (10) float2 pairs of div_term
    nfloat4* __restrict__ out4)          // (524288*30) float4
{
    const int rem = threadIdx.x;                         // 0..29
    const int ty  = threadIdx.y;                         // 0..31

    const int c  = (rem * 205) >> 11;                    // rem/10: 0,1,2
    const int kp = rem - 10 * c;                         // pair index 0..9

    const float2 d  = div2[kp];
    const float m0  = d.x * INV_2PI;                     // fold revolutions scale
    const float m1  = d.y * INV_2PI;

    const int base = blockIdx.x * (32 * PPT) + ty;       // first position

#pragma unroll
    for (int jo = 0; jo < PPT / CHUNK; ++jo) {
        // Issue a batch of loads first (ILP; 8 outstanding loads per lane)
        float p[CHUNK];
#pragma unroll
        for (int i = 0; i < CHUNK; ++i) {
            const float4 xv = x4[base + 32 * (jo * CHUNK + i)];  // L1 broadcast
            p[i] = (c == 0) ? xv.y : (c == 1) ? xv.z : xv.w;
        }

#pragma unroll
        for (int i = 0; i < CHUNK; ++i) {
            const float r0 = p[i] * m0;
            const float r1 = p[i] * m1;
            nfloat4 v;
            v.x = __builtin_amdgcn_sinf(r0);
            v.y = __builtin_amdgcn_cosf(r0);
            v.z = __builtin_amdgcn_sinf(r1);
            v.w = __builtin_amdgcn_cosf(r1);
            // wave: 1 KB contiguous, 128B-aligned; nt -> no cache allocate
            __builtin_nontemporal_store(
                v, out4 + (base + 32 * (jo * CHUNK + i)) * 30 + rem);
        }
    }
}

extern "C" void kernel_launch(void* const* d_in, const int* in_sizes, int n_in,
                              void* d_out, int out_size, void* d_ws, size_t ws_size,
                              hipStream_t stream) {
    const float4* x4   = (const float4*)d_in[0];   // 524288 x float4
    const float2* div2 = (const float2*)d_in[1];   // 10 x float2
    nfloat4* out4      = (nfloat4*)d_out;          // 15,728,640 x float4

    const int positions = in_sizes[0] / 4;         // 524288
    dim3 block(30, 32);                            // 960 = 15 waves
    dim3 grid(positions / (32 * PPT));             // 1024 blocks
    Embed3D_kernel<<<grid, block, 0, stream>>>(x4, div2, out4);
}

// Round 3
// 260.870 us; speedup vs baseline: 1.0265x; 1.0265x over previous
//
#include <hip/hip_runtime.h>

// Embed3D: out[n,l, c*40 + 2k + {0,1}] = {sin,cos}(x[n,l,1+c] * div_term[k])
// 524288 positions x 120 floats. One thread per (rem, position-set):
// rem = which of the 30 float4s per position; each thread handles PPT=16
// positions (stride 32), processed in 2 chunks of 8.
// Block (30,32) = 15 waves; every wave store is a 1024-B-aligned 1024-B
// contiguous block (480B/pos x 32 pos = 15 KB per block-iter, block spans
// start at multiples of 1024B) -> store geometry identical to rocclr fill.
// R2 lesson: NON-TEMPORAL stores REGRESSED (+10us). Output (251.7 MB) fits
// the 256-MB L3; write-back stores let the dirty drain overlap subsequent
// graph nodes, while nt forces all bytes to HBM inside the kernel. Reverted.

constexpr float INV_2PI = 0.15915494309189535f;  // hw v_sin/v_cos take revolutions
constexpr int PPT   = 16;                        // positions per thread
constexpr int CHUNK = 8;                         // load/compute batch (VGPR control)

__global__ __launch_bounds__(960) void Embed3D_kernel(
    const float4* __restrict__ x4,       // (524288) float4: [.,p1,p2,p3]
    const float2* __restrict__ div2,     // (10) float2 pairs of div_term
    float4* __restrict__ out4)           // (524288*30) float4
{
    const int rem = threadIdx.x;                         // 0..29
    const int ty  = threadIdx.y;                         // 0..31

    const int c  = (rem * 205) >> 11;                    // rem/10: 0,1,2
    const int kp = rem - 10 * c;                         // pair index 0..9

    const float2 d  = div2[kp];
    const float m0  = d.x * INV_2PI;                     // fold revolutions scale
    const float m1  = d.y * INV_2PI;

    const int base = blockIdx.x * (32 * PPT) + ty;       // first position

#pragma unroll
    for (int jo = 0; jo < PPT / CHUNK; ++jo) {
        // Issue a batch of loads first (ILP; 8 outstanding loads per lane)
        float p[CHUNK];
#pragma unroll
        for (int i = 0; i < CHUNK; ++i) {
            const float4 xv = x4[base + 32 * (jo * CHUNK + i)];  // L1 broadcast
            p[i] = (c == 0) ? xv.y : (c == 1) ? xv.z : xv.w;
        }

#pragma unroll
        for (int i = 0; i < CHUNK; ++i) {
            const float r0 = p[i] * m0;
            const float r1 = p[i] * m1;
            float4 v;
            v.x = __builtin_amdgcn_sinf(r0);
            v.y = __builtin_amdgcn_cosf(r0);
            v.z = __builtin_amdgcn_sinf(r1);
            v.w = __builtin_amdgcn_cosf(r1);
            out4[(base + 32 * (jo * CHUNK + i)) * 30 + rem] = v;  // 1KB/wave, write-back
        }
    }
}

extern "C" void kernel_launch(void* const* d_in, const int* in_sizes, int n_in,
                              void* d_out, int out_size, void* d_ws, size_t ws_size,
                              hipStream_t stream) {
    const float4* x4   = (const float4*)d_in[0];   // 524288 x float4
    const float2* div2 = (const float2*)d_in[1];   // 10 x float2
    float4* out4       = (float4*)d_out;           // 15,728,640 x float4

    const int positions = in_sizes[0] / 4;         // 524288
    dim3 block(30, 32);                            // 960 = 15 waves
    dim3 grid(positions / (32 * PPT));             // 1024 blocks
    Embed3D_kernel<<<grid, block, 0, stream>>>(x4, div2, out4);
}

// Round 4
// 258.255 us; speedup vs baseline: 1.0369x; 1.0101x over previous
//
#include <hip/hip_runtime.h>
#include <hip/hip_bf16.h>

// Embed3D: out[n,l, c*40 + 2k + {0,1}] = {sin,cos}(x[n,l,1+c] * div_term[k])
// 524288 positions x 120 floats. One thread per (rem, position-set):
// rem = which of the 30 float4s per position; each thread handles PPT=8
// positions (stride 32) -> 8 independent 16-B stores per thread, amortizing
// wave setup/turnover. Block (30,32) = 15 waves writes a fully contiguous
// 120-KB span; every wave store is a 1024-B-aligned 1024-B block.
//
// Session findings (R1-R3):
//  - Non-temporal stores: ~neutral on the kernel, +grab of HBM inside the
//    kernel lifetime -> net regression. The neutrality proves the kernel's
//    write stream is ALREADY HBM-bound near roofline (~41us for 252 MB),
//    not cache-allocate-throttled.
//  - PPT 8->16: no improvement (non-fill residual is harness reset overhead,
//    not kernel time).
//  - Remaining graph time = ~151us poison-fill + ~41us mandatory writes +
//    ~55-65us of tiny reset dispatches: all outside .cpp control.
// This is the measured-best configuration (257.5us); reverted exactly.

constexpr float INV_2PI = 0.15915494309189535f;  // hw v_sin/v_cos take revolutions
constexpr int PPT = 8;                           // positions per thread

__global__ __launch_bounds__(960) void Embed3D_kernel(
    const float4* __restrict__ x4,       // (524288) float4: [.,p1,p2,p3]
    const float2* __restrict__ div2,     // (10) float2 pairs of div_term
    float4* __restrict__ out4)           // (524288*30) float4
{
    const int rem = threadIdx.x;                         // 0..29
    const int ty  = threadIdx.y;                         // 0..31

    const int c  = (rem * 205) >> 11;                    // rem/10: 0,1,2
    const int kp = rem - 10 * c;                         // pair index 0..9

    const float2 d  = div2[kp];
    const float m0  = d.x * INV_2PI;                     // fold revolutions scale
    const float m1  = d.y * INV_2PI;

    const int base = blockIdx.x * (32 * PPT) + ty;       // first position

    // Issue all loads first (ILP; 8 outstanding loads per lane)
    float p[PPT];
#pragma unroll
    for (int i = 0; i < PPT; ++i) {
        const float4 xv = x4[base + 32 * i];             // L1 broadcast
        p[i] = (c == 0) ? xv.y : (c == 1) ? xv.z : xv.w;
    }

#pragma unroll
    for (int i = 0; i < PPT; ++i) {
        const float r0 = p[i] * m0;
        const float r1 = p[i] * m1;
        float4 v;
        v.x = __builtin_amdgcn_sinf(r0);
        v.y = __builtin_amdgcn_cosf(r0);
        v.z = __builtin_amdgcn_sinf(r1);
        v.w = __builtin_amdgcn_cosf(r1);
        out4[(base + 32 * i) * 30 + rem] = v;            // wave: 1 KB contiguous
    }
}

extern "C" void kernel_launch(void* const* d_in, const int* in_sizes, int n_in,
                              void* d_out, int out_size, void* d_ws, size_t ws_size,
                              hipStream_t stream) {
    const float4* x4   = (const float4*)d_in[0];   // 524288 x float4
    const float2* div2 = (const float2*)d_in[1];   // 10 x float2
    float4* out4       = (float4*)d_out;           // 15,728,640 x float4

    const int positions = in_sizes[0] / 4;         // 524288
    dim3 block(30, 32);                            // 960 = 15 waves
    dim3 grid(positions / (32 * PPT));             // 2048 blocks
    Embed3D_kernel<<<grid, block, 0, stream>>>(x4, div2, out4);
}